// Round 10
// baseline (333.435 us; speedup 1.0000x reference)
//
#include <hip/hip_runtime.h>

// Round 10: single-kernel (prep fused — each wave builds its MFMA A-frags from the
// raw fp32 weights at startup; no prep launch, no d_ws), steady-state loop unrolled
// x2 with literal parity (all LDS addresses loop-invariant), waves 5-6 dummy-MFMA
// trim. Otherwise identical cross-step layer pipeline to r9: ONE barrier per step,
// phase(ph) = {L1(ph), L2(ph-1), L3(ph-2), L4(ph-3)}, parity-double-buffered h/c.
// WG 512 x 8 batch, grid 256, 1 WG/CU.

typedef _Float16 f16x8 __attribute__((ext_vector_type(8)));
typedef float    f32x4 __attribute__((ext_vector_type(4)));

constexpr int BATCH   = 2048;
constexpr int H   = 51;
constexpr int XKP = 80;                   // xh k-stride in halves (160 B)

__device__ __forceinline__ float frcp(float x) { return __builtin_amdgcn_rcpf(x); }
__device__ __forceinline__ float sigmoid_f(float x) { float e = __expf(-x); return frcp(1.f + e); }
__device__ __forceinline__ float tanh_f(float x) {
    float e = __expf(2.f * x);       // ->inf gives 1, ->0 gives -1; no clamp needed
    return 1.f - 2.f * frcp(e + 1.f);
}

#define PIN16(x) { f32x4 _t = __builtin_bit_cast(f32x4, x); asm volatile("" : "+v"(_t)); x = __builtin_bit_cast(f16x8, _t); }
#define PIN4(x)  asm volatile("" : "+v"(x))

__global__ __launch_bounds__(512, 2) void lstm4_main(
    const float* __restrict__ input,
    const float* __restrict__ w_ih1, const float* __restrict__ w_hh1,
    const float* __restrict__ b_ih1, const float* __restrict__ b_hh1,
    const float* __restrict__ w_ih2, const float* __restrict__ w_hh2,
    const float* __restrict__ b_ih2, const float* __restrict__ b_hh2,
    const float* __restrict__ w_ih3, const float* __restrict__ w_hh3,
    const float* __restrict__ b_ih3, const float* __restrict__ b_hh3,
    const float* __restrict__ w_ih4, const float* __restrict__ w_hh4,
    const float* __restrict__ b_ih4, const float* __restrict__ b_hh4,
    float* __restrict__ out)
{
    // vectors: 0=h1(+x at k=51) 1=c1 2=h2 3=c2 4=h3 5=c3; [vec][parity][b][k]
    __shared__ __align__(16) _Float16 xh[6][2][8][XKP];   // 15360 B
    __shared__ float inl[8 * 260];                        //  8320 B

    const int tid  = threadIdx.x;
    const int wave = tid >> 6;
    const int lane = tid & 63;
    const int col  = lane & 15;    // C/D col = batch (cols 8-15 duplicate)
    const int rg   = lane >> 4;    // row-group / k-group
    const int bcol = lane & 7;

    const int tile0 = wave;
    const int tile1 = (wave < 5) ? (8 + wave) : wave;
    const bool two  = (wave < 5);

    // ---- build weight A-fragments in-kernel (gate-interleaved rows, as r7-r9) ----
    // frag(W, xcol, tile, kf): lane(row16=l&15, kgrp=l>>4) holds
    //   A[tile*16+row16][kf*32+kgrp*8 .. +7], row' = (kh%..): kh=tile*4+(row16>>2),
    //   q=row16&3, orig row = q*H+kh; col j==51 of pm0 carries w_ih1.
    auto BUILD = [&](const float* W, const float* xcol, int tile, int kf) -> f16x8 {
        const int row16 = lane & 15, kgrp = lane >> 4;
        const int kbase = kf * 32 + kgrp * 8;
        const int kh = tile * 4 + (row16 >> 2);
        const int q  = row16 & 3;
        const int orow = q * H + kh;
        f16x8 v;
#pragma unroll
        for (int e = 0; e < 8; ++e) {
            const int j = kbase + e;
            float val = 0.f;
            if (kh < H) {
                if (j < H)             val = W[orow * H + j];
                else if (j == H && xcol) val = xcol[orow];
            }
            v[e] = (_Float16)val;
        }
        return v;
    };
    auto BUILD4 = [&](int kf) -> f16x8 {
        const int row16 = lane & 15, kgrp = lane >> 4;
        const int kbase = kf * 32 + kgrp * 8;
        f16x8 v;
#pragma unroll
        for (int e = 0; e < 8; ++e) {
            const int j = kbase + e;
            v[e] = (_Float16)((row16 < 4 && j < H) ? w_ih4[row16 * H + j] : 0.f);
        }
        return v;
    };

    f16x8 fA_0k0  = BUILD(w_hh1, w_ih1, tile0, 0), fA_0k1  = BUILD(w_hh1, w_ih1, tile0, 1);
    f16x8 fA_1k0  = BUILD(w_hh1, w_ih1, tile1, 0), fA_1k1  = BUILD(w_hh1, w_ih1, tile1, 1);
    f16x8 fI2_0k0 = BUILD(w_ih2, nullptr, tile0, 0), fI2_0k1 = BUILD(w_ih2, nullptr, tile0, 1);
    f16x8 fI2_1k0 = BUILD(w_ih2, nullptr, tile1, 0), fI2_1k1 = BUILD(w_ih2, nullptr, tile1, 1);
    f16x8 fH2_0k0 = BUILD(w_hh2, nullptr, tile0, 0), fH2_0k1 = BUILD(w_hh2, nullptr, tile0, 1);
    f16x8 fH2_1k0 = BUILD(w_hh2, nullptr, tile1, 0), fH2_1k1 = BUILD(w_hh2, nullptr, tile1, 1);
    f16x8 fI3_0k0 = BUILD(w_ih3, nullptr, tile0, 0), fI3_0k1 = BUILD(w_ih3, nullptr, tile0, 1);
    f16x8 fI3_1k0 = BUILD(w_ih3, nullptr, tile1, 0), fI3_1k1 = BUILD(w_ih3, nullptr, tile1, 1);
    f16x8 fH3_0k0 = BUILD(w_hh3, nullptr, tile0, 0), fH3_0k1 = BUILD(w_hh3, nullptr, tile0, 1);
    f16x8 fH3_1k0 = BUILD(w_hh3, nullptr, tile1, 0), fH3_1k1 = BUILD(w_hh3, nullptr, tile1, 1);
    f16x8 fL4k0 = BUILD4(0), fL4k1 = BUILD4(1);
    PIN16(fA_0k0);  PIN16(fA_0k1);  PIN16(fA_1k0);  PIN16(fA_1k1);
    PIN16(fI2_0k0); PIN16(fI2_0k1); PIN16(fI2_1k0); PIN16(fI2_1k1);
    PIN16(fH2_0k0); PIN16(fH2_0k1); PIN16(fH2_1k0); PIN16(fH2_1k1);
    PIN16(fI3_0k0); PIN16(fI3_0k1); PIN16(fI3_1k0); PIN16(fI3_1k1);
    PIN16(fH3_0k0); PIN16(fH3_0k1); PIN16(fH3_1k0); PIN16(fH3_1k1);
    PIN16(fL4k0);   PIN16(fL4k1);

    // ---- bias vectors (MFMA C-init; pinned) ----
    const int k0 = tile0 * 4 + rg;
    const int k1 = tile1 * 4 + rg;
    const bool k1v = two && (k1 < H);
    f32x4 cb1v0, cb1v1, cb2v0, cb2v1, cb3v0, cb3v1;
#pragma unroll
    for (int q = 0; q < 4; ++q) {
        cb1v0[q] = b_ih1[q * H + k0] + b_hh1[q * H + k0];
        cb2v0[q] = b_ih2[q * H + k0] + b_hh2[q * H + k0];
        cb3v0[q] = b_ih3[q * H + k0] + b_hh3[q * H + k0];
        cb1v1[q] = k1v ? (b_ih1[q * H + k1] + b_hh1[q * H + k1]) : 0.f;
        cb2v1[q] = k1v ? (b_ih2[q * H + k1] + b_hh2[q * H + k1]) : 0.f;
        cb3v1[q] = k1v ? (b_ih3[q * H + k1] + b_hh3[q * H + k1]) : 0.f;
    }
    PIN4(cb1v0); PIN4(cb1v1); PIN4(cb2v0); PIN4(cb2v1); PIN4(cb3v0); PIN4(cb3v1);
    float bias4v[4], whh4v[4];
#pragma unroll
    for (int q = 0; q < 4; ++q) {
        bias4v[q] = b_ih4[q] + b_hh4[q];
        whh4v[q]  = w_hh4[q];
    }

    // ---- stage input, zero x-vectors, stage x(0) ----
    {
        const float4 iv = *(const float4*)(input + (size_t)blockIdx.x * 2048 + tid * 4);
        *(float4*)(inl + (tid >> 6) * 260 + (tid & 63) * 4) = iv;
    }
    for (int i = tid; i < 6 * 2 * 8 * XKP; i += 512) ((_Float16*)xh)[i] = (_Float16)0.f;
    __syncthreads();
    if (tid < 8) xh[0][1][tid][H] = (_Float16)inl[tid * 260];   // x(0) -> parity 1
    __syncthreads();

    // per-lane states: col<8 -> (k0, b=col); col>=8 -> (k1, b=col-8)
    float c1s = 0.f, c2s = 0.f, c3s = 0.f;
    float h4 = 0.f, c4 = 0.f;   // wave 7, lanes 0-7

    auto mm = [](f16x8 A, f16x8 B, f32x4 C) {
        return __builtin_amdgcn_mfma_f32_16x16x32_f16(A, B, C, 0, 0, 0);
    };
    auto BF = [&](int v, int p, int kb) -> f16x8 {
        return *(const f16x8*)&xh[v][p][bcol][kb * 32 + rg * 8];
    };
    auto AS = [&](f32x4 a0, f32x4 a1, float& cs, int vh, int vc, int wp) {
        f32x4 a;
#pragma unroll
        for (int q = 0; q < 4; ++q) a[q] = (col < 8) ? a0[q] : a1[q];
        const float i_ = sigmoid_f(a[0]), f_ = sigmoid_f(a[1]);
        const float g_ = tanh_f(a[2]),    o_ = sigmoid_f(a[3]);
        cs = f_ * cs + i_ * g_;
        const float h = o_ * tanh_f(cs);
        const bool st = (col < 8) ? true : (two && k1 < H);
        const int kk = (col < 8) ? k0 : k1;
        if (st) {
            xh[vh][wp][col & 7][kk] = (_Float16)h;
            xh[vc][wp][col & 7][kk] = (_Float16)cs;
        }
    };
    auto L4FIN = [&](f32x4 la) {
        if (lane < 8) {
            const float i_ = sigmoid_f(la[0] + bias4v[0] + whh4v[0] * h4);
            const float f_ = sigmoid_f(la[1] + bias4v[1] + whh4v[1] * h4);
            const float g_ = tanh_f  (la[2] + bias4v[2] + whh4v[2] * h4);
            const float o_ = sigmoid_f(la[3] + bias4v[3] + whh4v[3] * h4);
            c4 = f_ * c4 + i_ * g_;
            h4 = o_ * tanh_f(c4);
        }
    };

    // branchy per-layer runners (fill/drain/epilogue phases only)
    auto runL1 = [&](int rp, int wp) {
        f16x8 b0 = BF(0, rp, 0), b1 = BF(0, rp, 1);
        f32x4 a0 = mm(fA_0k0, b0, cb1v0); a0 = mm(fA_0k1, b1, a0);
        f32x4 a1 = cb1v1;
        if (two) { a1 = mm(fA_1k0, b0, a1); a1 = mm(fA_1k1, b1, a1); }
        AS(a0, a1, c1s, 0, 1, wp);
    };
    auto runL2 = [&](int rx, int rh, int wp) {
        f16x8 x0 = BF(1, rx, 0), x1 = BF(1, rx, 1);
        f16x8 h0 = BF(2, rh, 0), h1f = BF(2, rh, 1);
        f32x4 a0 = mm(fH2_0k0, h0, cb2v0); a0 = mm(fH2_0k1, h1f, a0);
        a0 = mm(fI2_0k0, x0, a0); a0 = mm(fI2_0k1, x1, a0);
        f32x4 a1 = cb2v1;
        if (two) {
            a1 = mm(fH2_1k0, h0, a1); a1 = mm(fH2_1k1, h1f, a1);
            a1 = mm(fI2_1k0, x0, a1); a1 = mm(fI2_1k1, x1, a1);
        }
        AS(a0, a1, c2s, 2, 3, wp);
    };
    auto runL3 = [&](int rx, int rh, int wp) {
        f16x8 x0 = BF(3, rx, 0), x1 = BF(3, rx, 1);
        f16x8 h0 = BF(4, rh, 0), h1f = BF(4, rh, 1);
        f32x4 a0 = mm(fH3_0k0, h0, cb3v0); a0 = mm(fH3_0k1, h1f, a0);
        a0 = mm(fI3_0k0, x0, a0); a0 = mm(fI3_0k1, x1, a0);
        f32x4 a1 = cb3v1;
        if (two) {
            a1 = mm(fH3_1k0, h0, a1); a1 = mm(fH3_1k1, h1f, a1);
            a1 = mm(fI3_1k0, x0, a1); a1 = mm(fI3_1k1, x1, a1);
        }
        AS(a0, a1, c3s, 4, 5, wp);
    };
    auto runL4 = [&](int rp) {
        if (wave == 7) {
            f16x8 b0 = BF(5, rp, 0), b1 = BF(5, rp, 1);
            f32x4 la = {0.f, 0.f, 0.f, 0.f};
            la = mm(fL4k0, b0, la); la = mm(fL4k1, b1, la);
            L4FIN(la);
        }
    };
    auto stageX = [&](int ph) {   // stage x(ph+1) into parity ph&1
        if (wave == 6 && lane < 8 && ph <= 254)
            xh[0][ph & 1][lane][51] = (_Float16)inl[lane * 260 + ph + 1];
    };

    // steady-state phase body; pw passed as LITERAL so all LDS addrs fold
    auto STEP = [&](int pw, int ph) {
        f16x8 rA0 = BF(0, 1 - pw, 0), rA1 = BF(0, 1 - pw, 1);      // h1+x
        f16x8 r2x0 = BF(1, 1 - pw, 0), r2x1 = BF(1, 1 - pw, 1);    // c1
        f16x8 r2h0 = BF(2, pw, 0),     r2h1 = BF(2, pw, 1);        // h2
        f16x8 r3x0 = BF(3, pw, 0),     r3x1 = BF(3, pw, 1);        // c2
        f16x8 r3h0 = BF(4, 1 - pw, 0), r3h1 = BF(4, 1 - pw, 1);    // h3
        f32x4 a0 = mm(fA_0k0, rA0, cb1v0);   a0 = mm(fA_0k1, rA1, a0);
        f32x4 b0 = mm(fH2_0k0, r2h0, cb2v0); b0 = mm(fH2_0k1, r2h1, b0);
        b0 = mm(fI2_0k0, r2x0, b0);          b0 = mm(fI2_0k1, r2x1, b0);
        f32x4 d0 = mm(fH3_0k0, r3h0, cb3v0); d0 = mm(fH3_0k1, r3h1, d0);
        d0 = mm(fI3_0k0, r3x0, d0);          d0 = mm(fI3_0k1, r3x1, d0);
        f32x4 a1 = cb1v1, b1 = cb2v1, d1 = cb3v1;
        if (two) {         // real second tiles only (waves 5-6 no longer run dummies)
            a1 = mm(fA_1k0, rA0, a1);   a1 = mm(fA_1k1, rA1, a1);
            b1 = mm(fH2_1k0, r2h0, b1); b1 = mm(fH2_1k1, r2h1, b1);
            b1 = mm(fI2_1k0, r2x0, b1); b1 = mm(fI2_1k1, r2x1, b1);
            d1 = mm(fH3_1k0, r3h0, d1); d1 = mm(fH3_1k1, r3h1, d1);
            d1 = mm(fI3_1k0, r3x0, d1); d1 = mm(fI3_1k1, r3x1, d1);
        } else if (wave == 7) {   // L4(ph-3)
            f16x8 l0 = BF(5, 1 - pw, 0), l1 = BF(5, 1 - pw, 1);
            f32x4 la = {0.f, 0.f, 0.f, 0.f};
            la = mm(fL4k0, l0, la); la = mm(fL4k1, l1, la);
            L4FIN(la);
        }
        AS(a0, a1, c1s, 0, 1, pw);
        AS(b0, b1, c2s, 2, 3, 1 - pw);
        AS(d0, d1, c3s, 4, 5, pw);
        stageX(ph);
        __syncthreads();
    };

    // ---- fill phases 0..2 ----
    for (int ph = 0; ph <= 2; ++ph) {
        const int pw = ph & 1;
        runL1(1 - pw, pw);
        if (ph >= 1) runL2(1 - pw, pw, 1 - pw);
        if (ph >= 2) runL3(pw, 1 - pw, pw);
        stageX(ph);
        __syncthreads();
    }

    // ---- steady state: phases 3..255, unrolled x2 with literal parity ----
    for (int ph = 3; ph <= 253; ph += 2) {
        STEP(1, ph);
        STEP(0, ph + 1);
    }
    STEP(1, 255);

    // ---- drain phases 256..258 ----
    for (int ph = 256; ph <= 258; ++ph) {
        const int pw = ph & 1;
        if (ph <= 256) runL2(1 - pw, pw, 1 - pw);
        if (ph <= 257) runL3(pw, 1 - pw, pw);
        runL4(1 - pw);
        __syncthreads();
    }

    // ---- epilogue: feedback step (x = c4 after 256 input steps) ----
    if (wave == 7 && lane < 8) xh[0][1][lane][51] = (_Float16)c4;
    __syncthreads();
    runL1(1, 0); __syncthreads();       // L1(256)
    runL2(0, 1, 0); __syncthreads();    // L2(256)
    runL3(0, 1, 0); __syncthreads();    // L3(256)
    runL4(0);                           // L4(256) -> final c4
    if (wave == 7 && lane < 8) out[blockIdx.x * 8 + lane] = c4;
}

extern "C" void kernel_launch(void* const* d_in, const int* in_sizes, int n_in,
                              void* d_out, int out_size, void* d_ws, size_t ws_size,
                              hipStream_t stream) {
    const float* input = (const float*)d_in[0];
    const float* w_ih1 = (const float*)d_in[1];
    const float* w_hh1 = (const float*)d_in[2];
    const float* b_ih1 = (const float*)d_in[3];
    const float* b_hh1 = (const float*)d_in[4];
    const float* w_ih2 = (const float*)d_in[5];
    const float* w_hh2 = (const float*)d_in[6];
    const float* b_ih2 = (const float*)d_in[7];
    const float* b_hh2 = (const float*)d_in[8];
    const float* w_ih3 = (const float*)d_in[9];
    const float* w_hh3 = (const float*)d_in[10];
    const float* b_ih3 = (const float*)d_in[11];
    const float* b_hh3 = (const float*)d_in[12];
    const float* w_ih4 = (const float*)d_in[13];
    const float* w_hh4 = (const float*)d_in[14];
    const float* b_ih4 = (const float*)d_in[15];
    const float* b_hh4 = (const float*)d_in[16];

    hipLaunchKernelGGL(lstm4_main, dim3(BATCH / 8), dim3(512), 0, stream,
                       input,
                       w_ih1, w_hh1, b_ih1, b_hh1,
                       w_ih2, w_hh2, b_ih2, b_hh2,
                       w_ih3, w_hh3, b_ih3, b_hh3,
                       w_ih4, w_hh4, b_ih4, b_hh4,
                       (float*)d_out);
}